// Round 11
// baseline (309.232 us; speedup 1.0000x reference)
//
#include <hip/hip_runtime.h>
#include <hip/hip_bf16.h>

#define N_NODES 40000
#define N_EDGES 640000
#define NFEAT 128
#define NGRAPHS 64
#define ECAP 768   // LDS edge cache per 32-row block (mean 512, +11 sigma)

typedef __attribute__((ext_vector_type(8))) short short8;
typedef __attribute__((ext_vector_type(4))) float float4v;

static __device__ __forceinline__ float bf2f(unsigned short u) {
    unsigned int x = ((unsigned int)u) << 16;
    return __builtin_bit_cast(float, x);
}
static __device__ __forceinline__ unsigned short f2bf(float f) {
    unsigned int x = __builtin_bit_cast(unsigned int, f);
    unsigned int r = x + 0x7fffu + ((x >> 16) & 1u);
    return (unsigned short)(r >> 16);
}

// ---------------- CSR count + graph offsets + dtype casts (merged) ----------
__global__ void k_prep(const int* __restrict__ dst, int* __restrict__ deg,
                       const int* __restrict__ batch, int* __restrict__ goff,
                       const float* __restrict__ x, unsigned short* __restrict__ h0,
                       const float* __restrict__ Wl0, const float* __restrict__ Wr0,
                       const float* __restrict__ Wl1, const float* __restrict__ Wr1,
                       const float* __restrict__ Wl2, const float* __restrict__ Wr2,
                       unsigned short* __restrict__ Wt) {
    int b = blockIdx.x;
    if (b < 2500) {
        int e = b * 256 + threadIdx.x;
        if (e < N_EDGES) atomicAdd(&deg[dst[e]], 1);
    } else if (b < 2657) {
        int i = (b - 2500) * 256 + threadIdx.x;
        if (i >= N_NODES) return;
        int b1 = batch[i];
        int b0 = (i == 0) ? -1 : batch[i - 1];
        for (int g = b0 + 1; g <= b1; ++g) goff[g] = i;
        if (i == N_NODES - 1)
            for (int g = b1 + 1; g <= NGRAPHS; ++g) goff[g] = N_NODES;
    } else if (b < 12657) {
        int i = (b - 2657) * 256 + threadIdx.x;
        const int n = N_NODES * NFEAT / 2;
        if (i < n) {
            float a = x[2 * i], c = x[2 * i + 1];
            unsigned int u = (unsigned int)f2bf(a) | ((unsigned int)f2bf(c) << 16);
            ((unsigned int*)h0)[i] = u;
        }
    } else {
        int id = (b - 12657) * 256 + threadIdx.x;
        if (id >= 3 * 128 * 256) return;
        int l   = id >> 15;
        int rem = id & 32767;
        int nn  = rem >> 8;
        int k   = rem & 255;
        const float* Wl = (l == 0) ? Wl0 : (l == 1) ? Wl1 : Wl2;
        const float* Wr = (l == 0) ? Wr0 : (l == 1) ? Wr1 : Wr2;
        float v = (k < 128) ? Wl[k * 128 + nn] : Wr[(k - 128) * 128 + nn];
        Wt[id] = f2bf(v);
    }
}

// ---------------- single-kernel scan (40 blocks, redundant prefix) ----------
__global__ __launch_bounds__(1024) void k_scan(const int* __restrict__ deg,
                                               int* __restrict__ offsets,
                                               int* __restrict__ cursor) {
    __shared__ int ws[16];
    __shared__ int s_boff;
    int tid = threadIdx.x;
    int b = blockIdx.x;
    int lane = tid & 63, wave = tid >> 6;

    int lim = b << 10;
    int s = 0;
    for (int i = tid; i < lim; i += 1024) s += deg[i];
    for (int d = 1; d < 64; d <<= 1) s += __shfl_xor(s, d, 64);
    if (lane == 0) ws[wave] = s;
    __syncthreads();
    if (tid == 0) {
        int t = 0;
        for (int w = 0; w < 16; ++w) t += ws[w];
        s_boff = t;
    }
    __syncthreads();
    int boff = s_boff;

    int i = (b << 10) + tid;
    int v = (i < N_NODES) ? deg[i] : 0;
    int incl = v;
    for (int d = 1; d < 64; d <<= 1) {
        int t = __shfl_up(incl, d, 64);
        if (lane >= d) incl += t;
    }
    __syncthreads();
    if (lane == 63) ws[wave] = incl;
    __syncthreads();
    if (wave == 0 && lane < 16) {
        int w = ws[lane];
        for (int d = 1; d < 16; d <<= 1) {
            int t = __shfl_up(w, d, 64);
            if (lane >= d) w += t;
        }
        ws[lane] = w;
    }
    __syncthreads();
    int waveOff = (wave == 0) ? 0 : ws[wave - 1];
    if (i < N_NODES) {
        int o = boff + waveOff + incl - v;
        offsets[i] = o;
        cursor[i]  = o;
    }
    if (b == 39 && tid == 0) offsets[N_NODES] = N_EDGES;
}

__global__ void k_fill(const int* __restrict__ src, const int* __restrict__ dst,
                       int* __restrict__ cursor, int* __restrict__ esrc) {
    int e = blockIdx.x * 256 + threadIdx.x;
    if (e < N_EDGES) {
        int d = dst[e];
        int p = atomicAdd(&cursor[d], 1);
        esrc[p] = src[e];
    }
}

// ---------------- fused SAGE layer: 4-pass column-blocked gather ------------
// Pass p gathers only bytes [p*64,(p+1)*64) of each neighbor row: working set
// 40000 x 64B = 2.5MB -> fully resident in each XCD's 4MB L2 -> ~200cyc
// latency instead of ~450cyc L3 blend. Same total lines/bytes as full-row.
// Lane map within 16-lane group: e4=lane>>2 edge slot (4 edges/instr),
// q4=lane&3 chunk of the quarter. shfl_xor(4,8) reduce AFTER loop (full exec).
__global__ __launch_bounds__(256, 8) void k_sage(
        const unsigned short* __restrict__ hin,
        const int* __restrict__ offsets,
        const int* __restrict__ esrc,
        const unsigned short* __restrict__ Wt,   // [128][256] n-major
        const float* __restrict__ bias,
        unsigned short* __restrict__ hout) {
    __shared__ __align__(16) unsigned short As[32][264];
    __shared__ int eidx[ECAP];
    int tid = threadIdx.x;
    int row0 = blockIdx.x * 32;

    int estart = offsets[row0];
    int ecnt   = offsets[row0 + 32] - estart;
    int staged = ecnt < ECAP ? ecnt : ECAP;

    // stage hin half (cols 128..255): 512 16B chunks, 2 per thread
    for (int p = 0; p < 2; ++p) {
        int ci = tid + p * 256;
        int r = ci >> 4, c8 = ci & 15;
        uint4 v = *(const uint4*)(hin + (size_t)(row0 + r) * 128 + c8 * 8);
        *(uint4*)(&As[r][128 + c8 * 8]) = v;
    }
    // stage edge indices, coalesced
    for (int t = tid; t < staged; t += 256) eidx[t] = esrc[estart + t];
    __syncthreads();

    // gather-aggregate into cols 0..127
    {
        int grp = tid >> 4;   // 16 groups; each does 2 nodes
        int l   = tid & 15;
        int e4  = l >> 2;     // edge slot 0..3
        int q4  = l & 3;      // 16B chunk within the 64B quarter
        for (int nn = 0; nn < 2; ++nn) {
            int r = nn * 16 + grp;
            int node = row0 + r;
            int beg = offsets[node], end = offsets[node + 1];
            int deg = end - beg;
            float inv = 1.f / (float)(deg > 1 ? deg : 1);
            bool fast = (end - estart <= staged);
            int lend = end - estart;
            int lbeg = beg - estart;

            for (int p = 0; p < 4; ++p) {
                int co = (p * 4 + q4) * 8;      // ushort offset within row
                float a[8];
                for (int i = 0; i < 8; ++i) a[i] = 0.f;
                auto acc8 = [&](uint4 u) {
                    a[0] += bf2f((unsigned short)(u.x & 0xffffu));
                    a[1] += bf2f((unsigned short)(u.x >> 16));
                    a[2] += bf2f((unsigned short)(u.y & 0xffffu));
                    a[3] += bf2f((unsigned short)(u.y >> 16));
                    a[4] += bf2f((unsigned short)(u.z & 0xffffu));
                    a[5] += bf2f((unsigned short)(u.z >> 16));
                    a[6] += bf2f((unsigned short)(u.w & 0xffffu));
                    a[7] += bf2f((unsigned short)(u.w >> 16));
                };
                if (fast) {
                    int lj = lbeg + e4;
                    for (; lj + 12 < lend; lj += 16) {
                        int s0 = eidx[lj], s1 = eidx[lj + 4];
                        int s2 = eidx[lj + 8], s3 = eidx[lj + 12];
                        uint4 u0 = *(const uint4*)(hin + (size_t)s0 * 128 + co);
                        uint4 u1 = *(const uint4*)(hin + (size_t)s1 * 128 + co);
                        uint4 u2 = *(const uint4*)(hin + (size_t)s2 * 128 + co);
                        uint4 u3 = *(const uint4*)(hin + (size_t)s3 * 128 + co);
                        acc8(u0); acc8(u1); acc8(u2); acc8(u3);
                    }
                    for (; lj < lend; lj += 4) {
                        int s = eidx[lj];
                        uint4 u = *(const uint4*)(hin + (size_t)s * 128 + co);
                        acc8(u);
                    }
                } else {
                    for (int j = beg + e4; j < end; j += 4) {
                        int s = esrc[j];
                        uint4 u = *(const uint4*)(hin + (size_t)s * 128 + co);
                        acc8(u);
                    }
                }
                // reduce across the 4 edge slots (lane bits 2,3); full exec here
                for (int i = 0; i < 8; ++i) {
                    a[i] += __shfl_xor(a[i], 4, 64);
                    a[i] += __shfl_xor(a[i], 8, 64);
                }
                if (e4 == 0) {
                    uint4 v;
                    v.x = (unsigned int)f2bf(a[0] * inv) | ((unsigned int)f2bf(a[1] * inv) << 16);
                    v.y = (unsigned int)f2bf(a[2] * inv) | ((unsigned int)f2bf(a[3] * inv) << 16);
                    v.z = (unsigned int)f2bf(a[4] * inv) | ((unsigned int)f2bf(a[5] * inv) << 16);
                    v.w = (unsigned int)f2bf(a[6] * inv) | ((unsigned int)f2bf(a[7] * inv) << 16);
                    *(uint4*)(&As[r][co]) = v;
                }
            }
        }
    }
    __syncthreads();

    // MFMA: 32x128 tile, K=256
    int wave = tid >> 6, lane = tid & 63;
    int quad = lane >> 4, l16 = lane & 15;
    float4v acc[2][2];
    for (int rt = 0; rt < 2; ++rt)
        for (int ct = 0; ct < 2; ++ct) acc[rt][ct] = {0.f, 0.f, 0.f, 0.f};

    int ncol0 = wave * 32;
    for (int kc = 0; kc < 8; ++kc) {
        int k0 = kc * 32 + quad * 8;
        short8 a[2], b[2];
        for (int rt = 0; rt < 2; ++rt)
            a[rt] = *(const short8*)(&As[rt * 16 + l16][k0]);
        for (int ct = 0; ct < 2; ++ct)
            b[ct] = *(const short8*)(Wt + (size_t)(ncol0 + ct * 16 + l16) * 256 + k0);
        for (int rt = 0; rt < 2; ++rt)
            for (int ct = 0; ct < 2; ++ct)
                acc[rt][ct] = __builtin_amdgcn_mfma_f32_16x16x32_bf16(
                    a[rt], b[ct], acc[rt][ct], 0, 0, 0);
    }

    for (int ct = 0; ct < 2; ++ct) {
        int col = ncol0 + ct * 16 + l16;
        float bv = bias[col];
        for (int rt = 0; rt < 2; ++rt) {
            int r0 = rt * 16 + quad * 4;
            for (int i = 0; i < 4; ++i) {
                float v = acc[rt][ct][i] + bv;
                v = v > 0.f ? v : 0.f;
                hout[(size_t)(row0 + r0 + i) * 128 + col] = f2bf(v);
            }
        }
    }
}

// ---------------- pooling: one block per (graph, layer), no atomics ---------
__global__ __launch_bounds__(256) void k_pool(const unsigned short* __restrict__ h1,
                                              const unsigned short* __restrict__ h2,
                                              const unsigned short* __restrict__ h3,
                                              const int* __restrict__ goff,
                                              float* __restrict__ pooled) {
    __shared__ float red[4][16][8];
    int b = blockIdx.x;
    int g = b / 3, aidx = b % 3;
    const unsigned short* h = (aidx == 0) ? h1 : (aidx == 1) ? h2 : h3;
    int beg = goff[g], end = goff[g + 1];
    int tid = threadIdx.x;
    int rp = tid >> 4;
    int ch = tid & 15;
    float a[8];
    for (int i = 0; i < 8; ++i) a[i] = 0.f;
    for (int r = beg + rp; r < end; r += 16) {
        uint4 u = *(const uint4*)(h + (size_t)r * 128 + ch * 8);
        a[0] += bf2f((unsigned short)(u.x & 0xffffu));
        a[1] += bf2f((unsigned short)(u.x >> 16));
        a[2] += bf2f((unsigned short)(u.y & 0xffffu));
        a[3] += bf2f((unsigned short)(u.y >> 16));
        a[4] += bf2f((unsigned short)(u.z & 0xffffu));
        a[5] += bf2f((unsigned short)(u.z >> 16));
        a[6] += bf2f((unsigned short)(u.w & 0xffffu));
        a[7] += bf2f((unsigned short)(u.w >> 16));
    }
    for (int i = 0; i < 8; ++i) {
        a[i] += __shfl_xor(a[i], 16, 64);
        a[i] += __shfl_xor(a[i], 32, 64);
    }
    int wave = tid >> 6, lane = tid & 63;
    if (lane < 16)
        for (int i = 0; i < 8; ++i) red[wave][lane][i] = a[i];
    __syncthreads();
    if (tid < 128) {
        int ch2 = tid >> 3, e = tid & 7;
        float s = red[0][ch2][e] + red[1][ch2][e] + red[2][ch2][e] + red[3][ch2][e];
        pooled[g * 384 + aidx * 128 + ch2 * 8 + e] = s;
    }
}

// ---------------- final ----------------
__global__ void k_final(const float* __restrict__ pooled,
                        const float* __restrict__ Wlin,
                        const float* __restrict__ blin,
                        float* __restrict__ out) {
    int g = blockIdx.x, col = threadIdx.x;
    float acc = blin[col];
    for (int k = 0; k < 384; ++k)
        acc = fmaf(pooled[g * 384 + k], Wlin[k * 128 + col], acc);
    out[g * 128 + col] = acc > 0.f ? acc : 0.f;
}

extern "C" void kernel_launch(void* const* d_in, const int* in_sizes, int n_in,
                              void* d_out, int out_size, void* d_ws, size_t ws_size,
                              hipStream_t stream) {
    const float* x    = (const float*)d_in[0];
    const int*   ei   = (const int*)d_in[1];
    const int*   src  = ei;
    const int*   dst  = ei + N_EDGES;
    const int*   batch = (const int*)d_in[2];
    const float* W1l = (const float*)d_in[3];
    const float* b1  = (const float*)d_in[4];
    const float* W1r = (const float*)d_in[5];
    const float* W2l = (const float*)d_in[6];
    const float* b2  = (const float*)d_in[7];
    const float* W2r = (const float*)d_in[8];
    const float* W3l = (const float*)d_in[9];
    const float* b3  = (const float*)d_in[10];
    const float* W3r = (const float*)d_in[11];
    const float* Wlin = (const float*)d_in[12];
    const float* blin = (const float*)d_in[13];
    float* out = (float*)d_out;

    char* ws = (char*)d_ws;
    size_t off = 0;
    auto alloc = [&](size_t bytes) -> char* {
        char* p = ws + off;
        off = (off + bytes + 255) & ~(size_t)255;
        return p;
    };
    int* offsets = (int*)alloc((N_NODES + 1) * sizeof(int));
    int* cursor  = (int*)alloc(N_NODES * sizeof(int));
    int* deg     = (int*)alloc(N_NODES * sizeof(int));
    int* goff    = (int*)alloc((NGRAPHS + 1) * sizeof(int));
    int* esrc    = (int*)alloc(N_EDGES * sizeof(int));
    unsigned short* h0   = (unsigned short*)alloc((size_t)N_NODES * 128 * 2);
    unsigned short* h1   = (unsigned short*)alloc((size_t)N_NODES * 128 * 2);
    unsigned short* h2   = (unsigned short*)alloc((size_t)N_NODES * 128 * 2);
    unsigned short* h3   = (unsigned short*)alloc((size_t)N_NODES * 128 * 2);
    unsigned short* Wt   = (unsigned short*)alloc(3 * 256 * 128 * 2);
    float* pooled = (float*)alloc(NGRAPHS * 384 * sizeof(float));

    hipMemsetAsync(deg, 0, N_NODES * sizeof(int), stream);

    k_prep<<<13041, 256, 0, stream>>>(dst, deg, batch, goff, x, h0,
                                      W1l, W1r, W2l, W2r, W3l, W3r, Wt);
    k_scan<<<40, 1024, 0, stream>>>(deg, offsets, cursor);
    k_fill<<<(N_EDGES + 255) / 256, 256, 0, stream>>>(src, dst, cursor, esrc);

    k_sage<<<1250, 256, 0, stream>>>(h0, offsets, esrc, Wt,             b1, h1);
    k_sage<<<1250, 256, 0, stream>>>(h1, offsets, esrc, Wt + 32768,     b2, h2);
    k_sage<<<1250, 256, 0, stream>>>(h2, offsets, esrc, Wt + 2 * 32768, b3, h3);

    k_pool<<<3 * NGRAPHS, 256, 0, stream>>>(h1, h2, h3, goff, pooled);
    k_final<<<NGRAPHS, 128, 0, stream>>>(pooled, Wlin, blin, out);
}

// Round 12
// 275.715 us; speedup vs baseline: 1.1216x; 1.1216x over previous
//
#include <hip/hip_runtime.h>
#include <hip/hip_bf16.h>

#define N_NODES 40000
#define N_EDGES 640000
#define NFEAT 128
#define NGRAPHS 64
#define ECAP 768   // LDS edge cache per 32-row block (mean 512, +11 sigma)

typedef __attribute__((ext_vector_type(8))) short short8;
typedef __attribute__((ext_vector_type(4))) float float4v;

static __device__ __forceinline__ float bf2f(unsigned short u) {
    unsigned int x = ((unsigned int)u) << 16;
    return __builtin_bit_cast(float, x);
}
static __device__ __forceinline__ unsigned short f2bf(float f) {
    unsigned int x = __builtin_bit_cast(unsigned int, f);
    unsigned int r = x + 0x7fffu + ((x >> 16) & 1u);
    return (unsigned short)(r >> 16);
}

// ---------------- CSR count + graph offsets + dtype casts (merged) ----------
__global__ void k_prep(const int* __restrict__ dst, int* __restrict__ deg,
                       const int* __restrict__ batch, int* __restrict__ goff,
                       const float* __restrict__ x, unsigned short* __restrict__ h0,
                       const float* __restrict__ Wl0, const float* __restrict__ Wr0,
                       const float* __restrict__ Wl1, const float* __restrict__ Wr1,
                       const float* __restrict__ Wl2, const float* __restrict__ Wr2,
                       unsigned short* __restrict__ Wt) {
    int b = blockIdx.x;
    if (b < 2500) {
        int e = b * 256 + threadIdx.x;
        if (e < N_EDGES) atomicAdd(&deg[dst[e]], 1);
    } else if (b < 2657) {
        int i = (b - 2500) * 256 + threadIdx.x;
        if (i >= N_NODES) return;
        int b1 = batch[i];
        int b0 = (i == 0) ? -1 : batch[i - 1];
        for (int g = b0 + 1; g <= b1; ++g) goff[g] = i;
        if (i == N_NODES - 1)
            for (int g = b1 + 1; g <= NGRAPHS; ++g) goff[g] = N_NODES;
    } else if (b < 12657) {
        int i = (b - 2657) * 256 + threadIdx.x;
        const int n = N_NODES * NFEAT / 2;
        if (i < n) {
            float a = x[2 * i], c = x[2 * i + 1];
            unsigned int u = (unsigned int)f2bf(a) | ((unsigned int)f2bf(c) << 16);
            ((unsigned int*)h0)[i] = u;
        }
    } else {
        int id = (b - 12657) * 256 + threadIdx.x;
        if (id >= 3 * 128 * 256) return;
        int l   = id >> 15;
        int rem = id & 32767;
        int nn  = rem >> 8;
        int k   = rem & 255;
        const float* Wl = (l == 0) ? Wl0 : (l == 1) ? Wl1 : Wl2;
        const float* Wr = (l == 0) ? Wr0 : (l == 1) ? Wr1 : Wr2;
        float v = (k < 128) ? Wl[k * 128 + nn] : Wr[(k - 128) * 128 + nn];
        Wt[id] = f2bf(v);
    }
}

// ---------------- single-kernel scan (40 blocks, redundant prefix) ----------
__global__ __launch_bounds__(1024) void k_scan(const int* __restrict__ deg,
                                               int* __restrict__ offsets,
                                               int* __restrict__ cursor) {
    __shared__ int ws[16];
    __shared__ int s_boff;
    int tid = threadIdx.x;
    int b = blockIdx.x;
    int lane = tid & 63, wave = tid >> 6;

    int lim = b << 10;
    int s = 0;
    for (int i = tid; i < lim; i += 1024) s += deg[i];
    for (int d = 1; d < 64; d <<= 1) s += __shfl_xor(s, d, 64);
    if (lane == 0) ws[wave] = s;
    __syncthreads();
    if (tid == 0) {
        int t = 0;
        for (int w = 0; w < 16; ++w) t += ws[w];
        s_boff = t;
    }
    __syncthreads();
    int boff = s_boff;

    int i = (b << 10) + tid;
    int v = (i < N_NODES) ? deg[i] : 0;
    int incl = v;
    for (int d = 1; d < 64; d <<= 1) {
        int t = __shfl_up(incl, d, 64);
        if (lane >= d) incl += t;
    }
    __syncthreads();
    if (lane == 63) ws[wave] = incl;
    __syncthreads();
    if (wave == 0 && lane < 16) {
        int w = ws[lane];
        for (int d = 1; d < 16; d <<= 1) {
            int t = __shfl_up(w, d, 64);
            if (lane >= d) w += t;
        }
        ws[lane] = w;
    }
    __syncthreads();
    int waveOff = (wave == 0) ? 0 : ws[wave - 1];
    if (i < N_NODES) {
        int o = boff + waveOff + incl - v;
        offsets[i] = o;
        cursor[i]  = o;
    }
    if (b == 39 && tid == 0) offsets[N_NODES] = N_EDGES;
}

__global__ void k_fill(const int* __restrict__ src, const int* __restrict__ dst,
                       int* __restrict__ cursor, int* __restrict__ esrc) {
    int e = blockIdx.x * 256 + threadIdx.x;
    if (e < N_EDGES) {
        int d = dst[e];
        int p = atomicAdd(&cursor[d], 1);
        esrc[p] = src[e];
    }
}

// ---------------- fused SAGE layer (R10 structure, 8 blocks/CU) -------------
// Full-row gather per 16-lane group, 8 loads in flight (the measured per-CU
// outstanding-line cap is the binding constraint; R11's column-blocking traded
// ILP for L2 residency and lost). LDS 19.97KB -> 8 blocks/CU.
__global__ __launch_bounds__(256, 8) void k_sage(
        const unsigned short* __restrict__ hin,
        const int* __restrict__ offsets,
        const int* __restrict__ esrc,
        const unsigned short* __restrict__ Wt,   // [128][256] n-major
        const float* __restrict__ bias,
        unsigned short* __restrict__ hout) {
    __shared__ __align__(16) unsigned short As[32][264];
    __shared__ int eidx[ECAP];
    int tid = threadIdx.x;
    int row0 = blockIdx.x * 32;

    int estart = offsets[row0];
    int ecnt   = offsets[row0 + 32] - estart;
    int staged = ecnt < ECAP ? ecnt : ECAP;

    // stage hin half (cols 128..255): 512 16B chunks, 2 per thread
    for (int p = 0; p < 2; ++p) {
        int ci = tid + p * 256;
        int r = ci >> 4, c8 = ci & 15;
        uint4 v = *(const uint4*)(hin + (size_t)(row0 + r) * 128 + c8 * 8);
        *(uint4*)(&As[r][128 + c8 * 8]) = v;
    }
    // stage edge indices, coalesced
    for (int t = tid; t < staged; t += 256) eidx[t] = esrc[estart + t];
    __syncthreads();

    // gather-aggregate into cols 0..127 (2 nodes per 16-lane group)
    {
        int grp = tid >> 4;   // 0..15
        int sub = tid & 15;   // 16B chunk of feature row
        for (int nn = 0; nn < 2; ++nn) {
            int r = nn * 16 + grp;
            int node = row0 + r;
            int beg = offsets[node], end = offsets[node + 1];
            float a[8];
            for (int i = 0; i < 8; ++i) a[i] = 0.f;
            auto acc8 = [&](uint4 u) {
                a[0] += bf2f((unsigned short)(u.x & 0xffffu));
                a[1] += bf2f((unsigned short)(u.x >> 16));
                a[2] += bf2f((unsigned short)(u.y & 0xffffu));
                a[3] += bf2f((unsigned short)(u.y >> 16));
                a[4] += bf2f((unsigned short)(u.z & 0xffffu));
                a[5] += bf2f((unsigned short)(u.z >> 16));
                a[6] += bf2f((unsigned short)(u.w & 0xffffu));
                a[7] += bf2f((unsigned short)(u.w >> 16));
            };
            if (end - estart <= staged) {          // indices in LDS
                int lj = beg - estart, lend = end - estart;
                for (; lj + 8 <= lend; lj += 8) {
                    int s0 = eidx[lj],     s1 = eidx[lj + 1];
                    int s2 = eidx[lj + 2], s3 = eidx[lj + 3];
                    int s4 = eidx[lj + 4], s5 = eidx[lj + 5];
                    int s6 = eidx[lj + 6], s7 = eidx[lj + 7];
                    uint4 u0 = *(const uint4*)(hin + (size_t)s0 * 128 + sub * 8);
                    uint4 u1 = *(const uint4*)(hin + (size_t)s1 * 128 + sub * 8);
                    uint4 u2 = *(const uint4*)(hin + (size_t)s2 * 128 + sub * 8);
                    uint4 u3 = *(const uint4*)(hin + (size_t)s3 * 128 + sub * 8);
                    uint4 u4 = *(const uint4*)(hin + (size_t)s4 * 128 + sub * 8);
                    uint4 u5 = *(const uint4*)(hin + (size_t)s5 * 128 + sub * 8);
                    uint4 u6 = *(const uint4*)(hin + (size_t)s6 * 128 + sub * 8);
                    uint4 u7 = *(const uint4*)(hin + (size_t)s7 * 128 + sub * 8);
                    acc8(u0); acc8(u1); acc8(u2); acc8(u3);
                    acc8(u4); acc8(u5); acc8(u6); acc8(u7);
                }
                for (; lj < lend; ++lj) {
                    int s = eidx[lj];
                    uint4 u = *(const uint4*)(hin + (size_t)s * 128 + sub * 8);
                    acc8(u);
                }
            } else {                               // overflow fallback
                for (int j = beg; j < end; ++j) {
                    int s = esrc[j];
                    uint4 u = *(const uint4*)(hin + (size_t)s * 128 + sub * 8);
                    acc8(u);
                }
            }
            int deg = end - beg;
            float inv = 1.f / (float)(deg > 1 ? deg : 1);
            uint4 v;
            v.x = (unsigned int)f2bf(a[0] * inv) | ((unsigned int)f2bf(a[1] * inv) << 16);
            v.y = (unsigned int)f2bf(a[2] * inv) | ((unsigned int)f2bf(a[3] * inv) << 16);
            v.z = (unsigned int)f2bf(a[4] * inv) | ((unsigned int)f2bf(a[5] * inv) << 16);
            v.w = (unsigned int)f2bf(a[6] * inv) | ((unsigned int)f2bf(a[7] * inv) << 16);
            *(uint4*)(&As[r][sub * 8]) = v;
        }
    }
    __syncthreads();

    // MFMA: 32x128 tile, K=256
    int wave = tid >> 6, lane = tid & 63;
    int quad = lane >> 4, l16 = lane & 15;
    float4v acc[2][2];
    for (int rt = 0; rt < 2; ++rt)
        for (int ct = 0; ct < 2; ++ct) acc[rt][ct] = {0.f, 0.f, 0.f, 0.f};

    int ncol0 = wave * 32;
    for (int kc = 0; kc < 8; ++kc) {
        int k0 = kc * 32 + quad * 8;
        short8 a[2], b[2];
        for (int rt = 0; rt < 2; ++rt)
            a[rt] = *(const short8*)(&As[rt * 16 + l16][k0]);
        for (int ct = 0; ct < 2; ++ct)
            b[ct] = *(const short8*)(Wt + (size_t)(ncol0 + ct * 16 + l16) * 256 + k0);
        for (int rt = 0; rt < 2; ++rt)
            for (int ct = 0; ct < 2; ++ct)
                acc[rt][ct] = __builtin_amdgcn_mfma_f32_16x16x32_bf16(
                    a[rt], b[ct], acc[rt][ct], 0, 0, 0);
    }

    for (int ct = 0; ct < 2; ++ct) {
        int col = ncol0 + ct * 16 + l16;
        float bv = bias[col];
        for (int rt = 0; rt < 2; ++rt) {
            int r0 = rt * 16 + quad * 4;
            for (int i = 0; i < 4; ++i) {
                float v = acc[rt][ct][i] + bv;
                v = v > 0.f ? v : 0.f;
                hout[(size_t)(row0 + r0 + i) * 128 + col] = f2bf(v);
            }
        }
    }
}

// ---------------- pooling: one block per (graph, layer), no atomics ---------
__global__ __launch_bounds__(256) void k_pool(const unsigned short* __restrict__ h1,
                                              const unsigned short* __restrict__ h2,
                                              const unsigned short* __restrict__ h3,
                                              const int* __restrict__ goff,
                                              float* __restrict__ pooled) {
    __shared__ float red[4][16][8];
    int b = blockIdx.x;
    int g = b / 3, aidx = b % 3;
    const unsigned short* h = (aidx == 0) ? h1 : (aidx == 1) ? h2 : h3;
    int beg = goff[g], end = goff[g + 1];
    int tid = threadIdx.x;
    int rp = tid >> 4;
    int ch = tid & 15;
    float a[8];
    for (int i = 0; i < 8; ++i) a[i] = 0.f;
    for (int r = beg + rp; r < end; r += 16) {
        uint4 u = *(const uint4*)(h + (size_t)r * 128 + ch * 8);
        a[0] += bf2f((unsigned short)(u.x & 0xffffu));
        a[1] += bf2f((unsigned short)(u.x >> 16));
        a[2] += bf2f((unsigned short)(u.y & 0xffffu));
        a[3] += bf2f((unsigned short)(u.y >> 16));
        a[4] += bf2f((unsigned short)(u.z & 0xffffu));
        a[5] += bf2f((unsigned short)(u.z >> 16));
        a[6] += bf2f((unsigned short)(u.w & 0xffffu));
        a[7] += bf2f((unsigned short)(u.w >> 16));
    }
    for (int i = 0; i < 8; ++i) {
        a[i] += __shfl_xor(a[i], 16, 64);
        a[i] += __shfl_xor(a[i], 32, 64);
    }
    int wave = tid >> 6, lane = tid & 63;
    if (lane < 16)
        for (int i = 0; i < 8; ++i) red[wave][lane][i] = a[i];
    __syncthreads();
    if (tid < 128) {
        int ch2 = tid >> 3, e = tid & 7;
        float s = red[0][ch2][e] + red[1][ch2][e] + red[2][ch2][e] + red[3][ch2][e];
        pooled[g * 384 + aidx * 128 + ch2 * 8 + e] = s;
    }
}

// ---------------- final ----------------
__global__ void k_final(const float* __restrict__ pooled,
                        const float* __restrict__ Wlin,
                        const float* __restrict__ blin,
                        float* __restrict__ out) {
    int g = blockIdx.x, col = threadIdx.x;
    float acc = blin[col];
    for (int k = 0; k < 384; ++k)
        acc = fmaf(pooled[g * 384 + k], Wlin[k * 128 + col], acc);
    out[g * 128 + col] = acc > 0.f ? acc : 0.f;
}

extern "C" void kernel_launch(void* const* d_in, const int* in_sizes, int n_in,
                              void* d_out, int out_size, void* d_ws, size_t ws_size,
                              hipStream_t stream) {
    const float* x    = (const float*)d_in[0];
    const int*   ei   = (const int*)d_in[1];
    const int*   src  = ei;
    const int*   dst  = ei + N_EDGES;
    const int*   batch = (const int*)d_in[2];
    const float* W1l = (const float*)d_in[3];
    const float* b1  = (const float*)d_in[4];
    const float* W1r = (const float*)d_in[5];
    const float* W2l = (const float*)d_in[6];
    const float* b2  = (const float*)d_in[7];
    const float* W2r = (const float*)d_in[8];
    const float* W3l = (const float*)d_in[9];
    const float* b3  = (const float*)d_in[10];
    const float* W3r = (const float*)d_in[11];
    const float* Wlin = (const float*)d_in[12];
    const float* blin = (const float*)d_in[13];
    float* out = (float*)d_out;

    char* ws = (char*)d_ws;
    size_t off = 0;
    auto alloc = [&](size_t bytes) -> char* {
        char* p = ws + off;
        off = (off + bytes + 255) & ~(size_t)255;
        return p;
    };
    int* offsets = (int*)alloc((N_NODES + 1) * sizeof(int));
    int* cursor  = (int*)alloc(N_NODES * sizeof(int));
    int* deg     = (int*)alloc(N_NODES * sizeof(int));
    int* goff    = (int*)alloc((NGRAPHS + 1) * sizeof(int));
    int* esrc    = (int*)alloc(N_EDGES * sizeof(int));
    unsigned short* h0   = (unsigned short*)alloc((size_t)N_NODES * 128 * 2);
    unsigned short* h1   = (unsigned short*)alloc((size_t)N_NODES * 128 * 2);
    unsigned short* h2   = (unsigned short*)alloc((size_t)N_NODES * 128 * 2);
    unsigned short* h3   = (unsigned short*)alloc((size_t)N_NODES * 128 * 2);
    unsigned short* Wt   = (unsigned short*)alloc(3 * 256 * 128 * 2);
    float* pooled = (float*)alloc(NGRAPHS * 384 * sizeof(float));

    hipMemsetAsync(deg, 0, N_NODES * sizeof(int), stream);

    k_prep<<<13041, 256, 0, stream>>>(dst, deg, batch, goff, x, h0,
                                      W1l, W1r, W2l, W2r, W3l, W3r, Wt);
    k_scan<<<40, 1024, 0, stream>>>(deg, offsets, cursor);
    k_fill<<<(N_EDGES + 255) / 256, 256, 0, stream>>>(src, dst, cursor, esrc);

    k_sage<<<1250, 256, 0, stream>>>(h0, offsets, esrc, Wt,             b1, h1);
    k_sage<<<1250, 256, 0, stream>>>(h1, offsets, esrc, Wt + 32768,     b2, h2);
    k_sage<<<1250, 256, 0, stream>>>(h2, offsets, esrc, Wt + 2 * 32768, b3, h3);

    k_pool<<<3 * NGRAPHS, 256, 0, stream>>>(h1, h2, h3, goff, pooled);
    k_final<<<NGRAPHS, 128, 0, stream>>>(pooled, Wlin, blin, out);
}

// Round 13
// 263.719 us; speedup vs baseline: 1.1726x; 1.0455x over previous
//
#include <hip/hip_runtime.h>
#include <hip/hip_bf16.h>

#define N_NODES 40000
#define N_EDGES 640000
#define NFEAT 128
#define NGRAPHS 64
#define ECAP 768   // LDS edge cache per 32-row block (mean 512, +11 sigma)

typedef __attribute__((ext_vector_type(8))) short short8;
typedef __attribute__((ext_vector_type(4))) float float4v;

static __device__ __forceinline__ float bf2f(unsigned short u) {
    unsigned int x = ((unsigned int)u) << 16;
    return __builtin_bit_cast(float, x);
}
static __device__ __forceinline__ unsigned short f2bf(float f) {
    unsigned int x = __builtin_bit_cast(unsigned int, f);
    unsigned int r = x + 0x7fffu + ((x >> 16) & 1u);
    return (unsigned short)(r >> 16);
}

// ---- prep: edge count | goff | cast x (uint4) | cast W | zero pooled -------
// blocks: [0,2500) count, [2500,2657) goff, [2657,5157) castx,
//         [5157,5541) castw, [5541,5637) zero pooled
__global__ void k_prep(const int* __restrict__ dst, int* __restrict__ deg,
                       const int* __restrict__ batch, int* __restrict__ goff,
                       const float* __restrict__ x, unsigned short* __restrict__ h0,
                       const float* __restrict__ Wl0, const float* __restrict__ Wr0,
                       const float* __restrict__ Wl1, const float* __restrict__ Wr1,
                       const float* __restrict__ Wl2, const float* __restrict__ Wr2,
                       unsigned short* __restrict__ Wt, float* __restrict__ pooled) {
    int b = blockIdx.x;
    if (b < 2500) {
        int e = b * 256 + threadIdx.x;
        if (e < N_EDGES) atomicAdd(&deg[dst[e]], 1);
    } else if (b < 2657) {
        int i = (b - 2500) * 256 + threadIdx.x;
        if (i >= N_NODES) return;
        int b1 = batch[i];
        int b0 = (i == 0) ? -1 : batch[i - 1];
        for (int g = b0 + 1; g <= b1; ++g) goff[g] = i;
        if (i == N_NODES - 1)
            for (int g = b1 + 1; g <= NGRAPHS; ++g) goff[g] = N_NODES;
    } else if (b < 5157) {
        int i = (b - 2657) * 256 + threadIdx.x;   // uint4 index (8 bf16)
        const int n = N_NODES * NFEAT / 8;
        if (i < n) {
            const float4* xf = (const float4*)x;
            float4 p0 = xf[2 * i], p1 = xf[2 * i + 1];
            uint4 v;
            v.x = (unsigned int)f2bf(p0.x) | ((unsigned int)f2bf(p0.y) << 16);
            v.y = (unsigned int)f2bf(p0.z) | ((unsigned int)f2bf(p0.w) << 16);
            v.z = (unsigned int)f2bf(p1.x) | ((unsigned int)f2bf(p1.y) << 16);
            v.w = (unsigned int)f2bf(p1.z) | ((unsigned int)f2bf(p1.w) << 16);
            ((uint4*)h0)[i] = v;
        }
    } else if (b < 5541) {
        int id = (b - 5157) * 256 + threadIdx.x;
        if (id >= 3 * 128 * 256) return;
        int l   = id >> 15;
        int rem = id & 32767;
        int nn  = rem >> 8;
        int k   = rem & 255;
        const float* Wl = (l == 0) ? Wl0 : (l == 1) ? Wl1 : Wl2;
        const float* Wr = (l == 0) ? Wr0 : (l == 1) ? Wr1 : Wr2;
        float v = (k < 128) ? Wl[k * 128 + nn] : Wr[(k - 128) * 128 + nn];
        Wt[id] = f2bf(v);
    } else {
        int j = (b - 5541) * 256 + threadIdx.x;
        if (j < NGRAPHS * 384) pooled[j] = 0.f;
    }
}

// ---------------- single-kernel scan (40 blocks, redundant prefix) ----------
__global__ __launch_bounds__(1024) void k_scan(const int* __restrict__ deg,
                                               int* __restrict__ offsets,
                                               int* __restrict__ cursor) {
    __shared__ int ws[16];
    __shared__ int s_boff;
    int tid = threadIdx.x;
    int b = blockIdx.x;
    int lane = tid & 63, wave = tid >> 6;

    int lim = b << 10;
    int s = 0;
    for (int i = tid; i < lim; i += 1024) s += deg[i];
    for (int d = 1; d < 64; d <<= 1) s += __shfl_xor(s, d, 64);
    if (lane == 0) ws[wave] = s;
    __syncthreads();
    if (tid == 0) {
        int t = 0;
        for (int w = 0; w < 16; ++w) t += ws[w];
        s_boff = t;
    }
    __syncthreads();
    int boff = s_boff;

    int i = (b << 10) + tid;
    int v = (i < N_NODES) ? deg[i] : 0;
    int incl = v;
    for (int d = 1; d < 64; d <<= 1) {
        int t = __shfl_up(incl, d, 64);
        if (lane >= d) incl += t;
    }
    __syncthreads();
    if (lane == 63) ws[wave] = incl;
    __syncthreads();
    if (wave == 0 && lane < 16) {
        int w = ws[lane];
        for (int d = 1; d < 16; d <<= 1) {
            int t = __shfl_up(w, d, 64);
            if (lane >= d) w += t;
        }
        ws[lane] = w;
    }
    __syncthreads();
    int waveOff = (wave == 0) ? 0 : ws[wave - 1];
    if (i < N_NODES) {
        int o = boff + waveOff + incl - v;
        offsets[i] = o;
        cursor[i]  = o;
    }
    if (b == 39 && tid == 0) offsets[N_NODES] = N_EDGES;
}

__global__ void k_fill(const int* __restrict__ src, const int* __restrict__ dst,
                       int* __restrict__ cursor, int* __restrict__ esrc) {
    int e = blockIdx.x * 256 + threadIdx.x;
    if (e < N_EDGES) {
        int d = dst[e];
        int p = atomicAdd(&cursor[d], 1);
        esrc[p] = src[e];
    }
}

// ---------------- fused SAGE layer + pooled epilogue ------------------------
// R12 gather/MFMA structure (8 blocks/CU). Epilogue: f32 outputs go to an LDS
// tile aliasing As, segment-reduced by (sorted) graph id, one atomicAdd per
// (graph,col) run. hout==nullptr for layer 3 (h3 only feeds pooling).
__global__ __launch_bounds__(256, 8) void k_sage(
        const unsigned short* __restrict__ hin,
        const int* __restrict__ offsets,
        const int* __restrict__ esrc,
        const int* __restrict__ batch,
        const unsigned short* __restrict__ Wt,   // [128][256] n-major
        const float* __restrict__ bias,
        unsigned short* __restrict__ hout,       // nullable
        float* __restrict__ poolseg) {           // pooled + layer*128
    __shared__ __align__(16) unsigned short As[32][264];
    __shared__ int eidx[ECAP];
    int tid = threadIdx.x;
    int row0 = blockIdx.x * 32;

    int estart = offsets[row0];
    int ecnt   = offsets[row0 + 32] - estart;
    int staged = ecnt < ECAP ? ecnt : ECAP;

    // stage hin half (cols 128..255)
    for (int p = 0; p < 2; ++p) {
        int ci = tid + p * 256;
        int r = ci >> 4, c8 = ci & 15;
        uint4 v = *(const uint4*)(hin + (size_t)(row0 + r) * 128 + c8 * 8);
        *(uint4*)(&As[r][128 + c8 * 8]) = v;
    }
    for (int t = tid; t < staged; t += 256) eidx[t] = esrc[estart + t];
    __syncthreads();

    // gather-aggregate into cols 0..127 (2 nodes per 16-lane group)
    {
        int grp = tid >> 4;
        int sub = tid & 15;
        for (int nn = 0; nn < 2; ++nn) {
            int r = nn * 16 + grp;
            int node = row0 + r;
            int beg = offsets[node], end = offsets[node + 1];
            float a[8];
            for (int i = 0; i < 8; ++i) a[i] = 0.f;
            auto acc8 = [&](uint4 u) {
                a[0] += bf2f((unsigned short)(u.x & 0xffffu));
                a[1] += bf2f((unsigned short)(u.x >> 16));
                a[2] += bf2f((unsigned short)(u.y & 0xffffu));
                a[3] += bf2f((unsigned short)(u.y >> 16));
                a[4] += bf2f((unsigned short)(u.z & 0xffffu));
                a[5] += bf2f((unsigned short)(u.z >> 16));
                a[6] += bf2f((unsigned short)(u.w & 0xffffu));
                a[7] += bf2f((unsigned short)(u.w >> 16));
            };
            if (end - estart <= staged) {
                int lj = beg - estart, lend = end - estart;
                for (; lj + 8 <= lend; lj += 8) {
                    int s0 = eidx[lj],     s1 = eidx[lj + 1];
                    int s2 = eidx[lj + 2], s3 = eidx[lj + 3];
                    int s4 = eidx[lj + 4], s5 = eidx[lj + 5];
                    int s6 = eidx[lj + 6], s7 = eidx[lj + 7];
                    uint4 u0 = *(const uint4*)(hin + (size_t)s0 * 128 + sub * 8);
                    uint4 u1 = *(const uint4*)(hin + (size_t)s1 * 128 + sub * 8);
                    uint4 u2 = *(const uint4*)(hin + (size_t)s2 * 128 + sub * 8);
                    uint4 u3 = *(const uint4*)(hin + (size_t)s3 * 128 + sub * 8);
                    uint4 u4 = *(const uint4*)(hin + (size_t)s4 * 128 + sub * 8);
                    uint4 u5 = *(const uint4*)(hin + (size_t)s5 * 128 + sub * 8);
                    uint4 u6 = *(const uint4*)(hin + (size_t)s6 * 128 + sub * 8);
                    uint4 u7 = *(const uint4*)(hin + (size_t)s7 * 128 + sub * 8);
                    acc8(u0); acc8(u1); acc8(u2); acc8(u3);
                    acc8(u4); acc8(u5); acc8(u6); acc8(u7);
                }
                for (; lj < lend; ++lj) {
                    int s = eidx[lj];
                    uint4 u = *(const uint4*)(hin + (size_t)s * 128 + sub * 8);
                    acc8(u);
                }
            } else {
                for (int j = beg; j < end; ++j) {
                    int s = esrc[j];
                    uint4 u = *(const uint4*)(hin + (size_t)s * 128 + sub * 8);
                    acc8(u);
                }
            }
            int deg = end - beg;
            float inv = 1.f / (float)(deg > 1 ? deg : 1);
            uint4 v;
            v.x = (unsigned int)f2bf(a[0] * inv) | ((unsigned int)f2bf(a[1] * inv) << 16);
            v.y = (unsigned int)f2bf(a[2] * inv) | ((unsigned int)f2bf(a[3] * inv) << 16);
            v.z = (unsigned int)f2bf(a[4] * inv) | ((unsigned int)f2bf(a[5] * inv) << 16);
            v.w = (unsigned int)f2bf(a[6] * inv) | ((unsigned int)f2bf(a[7] * inv) << 16);
            *(uint4*)(&As[r][sub * 8]) = v;
        }
    }
    __syncthreads();

    // MFMA: 32x128 tile, K=256
    int wave = tid >> 6, lane = tid & 63;
    int quad = lane >> 4, l16 = lane & 15;
    float4v acc[2][2];
    for (int rt = 0; rt < 2; ++rt)
        for (int ct = 0; ct < 2; ++ct) acc[rt][ct] = {0.f, 0.f, 0.f, 0.f};

    int ncol0 = wave * 32;
    for (int kc = 0; kc < 8; ++kc) {
        int k0 = kc * 32 + quad * 8;
        short8 a[2], b[2];
        for (int rt = 0; rt < 2; ++rt)
            a[rt] = *(const short8*)(&As[rt * 16 + l16][k0]);
        for (int ct = 0; ct < 2; ++ct)
            b[ct] = *(const short8*)(Wt + (size_t)(ncol0 + ct * 16 + l16) * 256 + k0);
        for (int rt = 0; rt < 2; ++rt)
            for (int ct = 0; ct < 2; ++ct)
                acc[rt][ct] = __builtin_amdgcn_mfma_f32_16x16x32_bf16(
                    a[rt], b[ct], acc[rt][ct], 0, 0, 0);
    }

    // ---- epilogue: bias+relu, optional hout store, fused pooling ----
    __syncthreads();                       // all As reads done; safe to alias
    float* Ps = (float*)&As[0][0];         // [32][132] f32 tile (16896 B fits)
    int* sbatch = eidx;                    // eidx no longer needed
    if (tid < 32) sbatch[tid] = batch[row0 + tid];

    for (int ct = 0; ct < 2; ++ct) {
        int col = ncol0 + ct * 16 + l16;
        float bv = bias[col];
        for (int rt = 0; rt < 2; ++rt) {
            int r0 = rt * 16 + quad * 4;
            for (int i = 0; i < 4; ++i) {
                float v = acc[rt][ct][i] + bv;
                v = v > 0.f ? v : 0.f;
                if (hout) hout[(size_t)(row0 + r0 + i) * 128 + col] = f2bf(v);
                Ps[(r0 + i) * 132 + col] = v;
            }
        }
    }
    __syncthreads();

    // segment-reduce 16 rows per half (batch sorted -> few runs per block)
    {
        int half = tid >> 7;               // 0: rows 0..15, 1: rows 16..31
        int c = tid & 127;
        int rbase = half * 16;
        float accp = 0.f;
        int cur = sbatch[rbase];
        for (int r = rbase; r < rbase + 16; ++r) {
            int g = sbatch[r];
            if (g != cur) {
                atomicAdd(&poolseg[cur * 384 + c], accp);
                accp = 0.f;
                cur = g;
            }
            accp += Ps[r * 132 + c];
        }
        atomicAdd(&poolseg[cur * 384 + c], accp);
    }
}

// ---------------- final ----------------
__global__ void k_final(const float* __restrict__ pooled,
                        const float* __restrict__ Wlin,
                        const float* __restrict__ blin,
                        float* __restrict__ out) {
    int g = blockIdx.x, col = threadIdx.x;
    float acc = blin[col];
    for (int k = 0; k < 384; ++k)
        acc = fmaf(pooled[g * 384 + k], Wlin[k * 128 + col], acc);
    out[g * 128 + col] = acc > 0.f ? acc : 0.f;
}

extern "C" void kernel_launch(void* const* d_in, const int* in_sizes, int n_in,
                              void* d_out, int out_size, void* d_ws, size_t ws_size,
                              hipStream_t stream) {
    const float* x    = (const float*)d_in[0];
    const int*   ei   = (const int*)d_in[1];
    const int*   src  = ei;
    const int*   dst  = ei + N_EDGES;
    const int*   batch = (const int*)d_in[2];
    const float* W1l = (const float*)d_in[3];
    const float* b1  = (const float*)d_in[4];
    const float* W1r = (const float*)d_in[5];
    const float* W2l = (const float*)d_in[6];
    const float* b2  = (const float*)d_in[7];
    const float* W2r = (const float*)d_in[8];
    const float* W3l = (const float*)d_in[9];
    const float* b3  = (const float*)d_in[10];
    const float* W3r = (const float*)d_in[11];
    const float* Wlin = (const float*)d_in[12];
    const float* blin = (const float*)d_in[13];
    float* out = (float*)d_out;

    char* ws = (char*)d_ws;
    size_t off = 0;
    auto alloc = [&](size_t bytes) -> char* {
        char* p = ws + off;
        off = (off + bytes + 255) & ~(size_t)255;
        return p;
    };
    int* offsets = (int*)alloc((N_NODES + 1) * sizeof(int));
    int* cursor  = (int*)alloc(N_NODES * sizeof(int));
    int* deg     = (int*)alloc(N_NODES * sizeof(int));
    int* goff    = (int*)alloc((NGRAPHS + 1) * sizeof(int));
    int* esrc    = (int*)alloc(N_EDGES * sizeof(int));
    unsigned short* h0   = (unsigned short*)alloc((size_t)N_NODES * 128 * 2);
    unsigned short* h1   = (unsigned short*)alloc((size_t)N_NODES * 128 * 2);
    unsigned short* h2   = (unsigned short*)alloc((size_t)N_NODES * 128 * 2);
    unsigned short* Wt   = (unsigned short*)alloc(3 * 256 * 128 * 2);
    float* pooled = (float*)alloc(NGRAPHS * 384 * sizeof(float));

    hipMemsetAsync(deg, 0, N_NODES * sizeof(int), stream);

    k_prep<<<5637, 256, 0, stream>>>(dst, deg, batch, goff, x, h0,
                                     W1l, W1r, W2l, W2r, W3l, W3r, Wt, pooled);
    k_scan<<<40, 1024, 0, stream>>>(deg, offsets, cursor);
    k_fill<<<(N_EDGES + 255) / 256, 256, 0, stream>>>(src, dst, cursor, esrc);

    k_sage<<<1250, 256, 0, stream>>>(h0, offsets, esrc, batch, Wt,
                                     b1, h1, pooled);
    k_sage<<<1250, 256, 0, stream>>>(h1, offsets, esrc, batch, Wt + 32768,
                                     b2, h2, pooled + 128);
    k_sage<<<1250, 256, 0, stream>>>(h2, offsets, esrc, batch, Wt + 2 * 32768,
                                     b3, (unsigned short*)nullptr, pooled + 256);

    k_final<<<NGRAPHS, 128, 0, stream>>>(pooled, Wlin, blin, out);
}